// Round 12
// baseline (129.135 us; speedup 1.0000x reference)
//
#include <hip/hip_runtime.h>
#include <cstdint>
#include <cstddef>

// 20-qubit statevector sim, 3 layers of [U3 x20 + CU3 ring (0,1)..(19,0)].
// R12 = R11 (127.5us) + FP16 inter-pass psi. R10/R11 established: pass
// count is the only lever (each pass ~6us fixed: ramp + L2-flush -> L3
// round trip), and 4 full passes + init2 is provably minimal (40 links /
// 12-per-pass max). Remaining controllable cost: inter-pass I/O bytes.
// FP32->FP16 halves them (16->8 MB/pass). Error budget: 4 roundings at
// ulp 4.9e-4 -> |dx| <= ~4e-4 per element, ~5x under the 2^-9 threshold.
// Internals of every pass stay full FP32; only the global psi buffers are
// half4 (2 complex amps / 8B granule, same granule-index layout as R11).
//
// Structure (6 dispatches): init2 (INIT+S1(0) in-LDS + handoff + S2(0)),
// S1(1), S2(1), S1(2), S2(2)+readout, fin_k.
// Pass internals (R3, verified): NT=512, v[4], 512 blocks, 11-bit tiles;
// window bits (0,1); rotate-by-1 x9 via LDS double-buffer (XOR-swizzle);
// U3+CU3 fused per phase (W0, W1 = u_c*U3 precomputed in LDS).
// S1(k): U3 q0..q10 + CU3 (0,1)..(9,10); S2(k): U3 q11..q19 + CU3
// (10,11)..(19,0), tile=(q10,...,q19,q0), block=(q1..q9).
// Inter-pass granule layout (verified): g = b + t0*2^9 + (t>>1)*2^10 +
// j0*2^18, content pairs over j1; reader loads 2 contiguous granules.
// init2 handoff: after S1(0), psi nonzero only at q11..q19=0; S2(0) block
// b synthesizes its 4 inputs from the stashed 2^11-amp psi1 in LDS:
// psi1_idx = (t>>8) + (b<<1) + (j<<10), nonzero only for (t&255)==0.
// Final readout: R = j0 + 2*rev9(t) + 1024*rev9(b) + 2^19*j1; block sum
// -> atomicAdd(accum); fin_k subtracts mean.

#define NB 512
#define NT 512
#define SW(i) ((i) ^ (((i) >> 3) & 1u))

typedef _Float16 h4 __attribute__((ext_vector_type(4)));  // 2 complex amps, 8B

__device__ __forceinline__ h4 pack2(float2 x, float2 y) {
  h4 r;
  r.x = (_Float16)x.x; r.y = (_Float16)x.y;
  r.z = (_Float16)y.x; r.w = (_Float16)y.y;
  return r;
}

__device__ __forceinline__ float2 cmadd2(float2 m0, float2 a0, float2 m1, float2 a1) {
  float2 r;
  r.x = m0.x * a0.x - m0.y * a0.y + m1.x * a1.x - m1.y * a1.y;
  r.y = m0.x * a0.y + m0.y * a0.x + m1.x * a1.y + m1.y * a1.x;
  return r;
}
__device__ __forceinline__ float2 cmul(float2 a, float2 b) {
  return make_float2(a.x * b.x - a.y * b.y, a.x * b.y + a.y * b.x);
}
__device__ __forceinline__ float2 cadd(float2 a, float2 b) {
  return make_float2(a.x + b.x, a.y + b.y);
}

// U3 on window bit0: pairs (0,1),(2,3)
__device__ __forceinline__ void applyU3b0(float2* v, const float2* m) {
  float2 m00 = m[0], m01 = m[1], m10 = m[2], m11 = m[3];
  float2 a0 = v[0], a1 = v[1];
  v[0] = cmadd2(m00, a0, m01, a1); v[1] = cmadd2(m10, a0, m11, a1);
  a0 = v[2]; a1 = v[3];
  v[2] = cmadd2(m00, a0, m01, a1); v[3] = cmadd2(m10, a0, m11, a1);
}
// fused [U3 on bit1, then CU3(ctrl=bit0,tgt=bit1)]: W0 acts on (v0,v2), W1 on (v1,v3)
__device__ __forceinline__ void applyF(float2* v, const float2* W0, const float2* W1) {
  float2 a0 = v[0], a1 = v[2];
  v[0] = cmadd2(W0[0], a0, W0[1], a1); v[2] = cmadd2(W0[2], a0, W0[3], a1);
  a0 = v[1]; a1 = v[3];
  v[1] = cmadd2(W1[0], a0, W1[1], a1); v[3] = cmadd2(W1[2], a0, W1[3], a1);
}
// raw CU3 ctrl bit0, tgt bit1: only (v1,v3)
__device__ __forceinline__ void applyC(float2* v, const float2* u) {
  float2 a0 = v[1], a1 = v[3];
  v[1] = cmadd2(u[0], a0, u[1], a1); v[3] = cmadd2(u[2], a0, u[3], a1);
}

__device__ __forceinline__ float xval(float2 a) {
  float p = a.x * a.x + a.y * a.y;
  return powf(0.8f * tanhf(52428.8f * p), 0.3f);
}

__device__ __forceinline__ void mat_from(const float* s, float2* m) {
  float st, ct, sl, cl, sp, cp, spl, cpl;
  sincosf(0.5f * s[0], &st, &ct);
  sincosf(s[2], &sl, &cl);
  sincosf(s[1], &sp, &cp);
  sincosf(s[1] + s[2], &spl, &cpl);
  m[0] = make_float2(ct, 0.f);
  m[1] = make_float2(-cl * st, -sl * st);
  m[2] = make_float2(cp * st, sp * st);
  m[3] = make_float2(cpl * ct, spl * ct);
}

// shared matrix stage: MU[q]=U3(q); MC[c]=u_c*U3(c+1) fused, MC[19]=raw u19.
__device__ __forceinline__ void load_mats(const float* u3p, const float* cu3p,
                                          int k, unsigned t, float2* MU, float2* MC) {
  if (t < 20) {
    mat_from(u3p + (k * 20 + t) * 3, MU + 4 * t);
  } else if (t >= 64 && t < 84) {
    unsigned c = t - 64;
    float2 u[4];
    mat_from(cu3p + (k * 20 + c) * 3, u);
    if (c == 19) {
      MC[76] = u[0]; MC[77] = u[1]; MC[78] = u[2]; MC[79] = u[3];
    } else {
      float2 ut[4];
      mat_from(u3p + (k * 20 + c + 1) * 3, ut);
      MC[4 * c + 0] = cadd(cmul(u[0], ut[0]), cmul(u[1], ut[2]));
      MC[4 * c + 1] = cadd(cmul(u[0], ut[1]), cmul(u[1], ut[3]));
      MC[4 * c + 2] = cadd(cmul(u[2], ut[0]), cmul(u[3], ut[2]));
      MC[4 * c + 3] = cadd(cmul(u[2], ut[1]), cmul(u[3], ut[3]));
    }
  }
}

// TYPE 0 = S1, 1 = S2; FINAL does readout.
template <int TYPE, int FINAL>
__global__ __launch_bounds__(NT, 4) void pass_k(const float* __restrict__ u3p,
                                                const float* __restrict__ cu3p, int k,
                                                const h4* __restrict__ in,
                                                h4* __restrict__ outPsi,
                                                float* __restrict__ accum,
                                                float* __restrict__ out) {
  __shared__ float4 A4[1024], B4[1024];  // rotation double-buffer (16 KB each)
  __shared__ float2 M[168];
  __shared__ float red[8];
  unsigned t = threadIdx.x, b = blockIdx.x;

  float2 v[4];
  {
    const h4* in4 = in + ((size_t)b << 10) + 2u * t;
    h4 f0 = in4[0], f1 = in4[1];
    v[0] = make_float2((float)f0.x, (float)f0.y);
    v[1] = make_float2((float)f0.z, (float)f0.w);
    v[2] = make_float2((float)f1.x, (float)f1.y);
    v[3] = make_float2((float)f1.z, (float)f1.w);
  }
  float2* MU = M;
  float2* MC = M + 80;
  load_mats(u3p, cu3p, k, t, MU, MC);
  __syncthreads();

#pragma unroll
  for (int p = 0; p < 10; ++p) {
    if (TYPE == 0) {
      if (p == 0) applyU3b0(v, MU);
      applyF(v, MU + 4 * (p + 1), MC + 4 * p);
    } else {
      if (p < 9) applyF(v, MU + 4 * (11 + p), MC + 4 * (10 + p));
      else       applyC(v, MC + 4 * 19);
    }
    if (p < 9) {
      float4* buf = (p & 1) ? B4 : A4;
      buf[SW(t)]        = make_float4(v[0].x, v[0].y, v[2].x, v[2].y);
      buf[SW(t + 512u)] = make_float4(v[1].x, v[1].y, v[3].x, v[3].y);
      __syncthreads();
      float4 fa = buf[SW(2u * t)], fb = buf[SW(2u * t + 1u)];
      v[0] = make_float2(fa.x, fa.y); v[1] = make_float2(fa.z, fa.w);
      v[2] = make_float2(fb.x, fb.y); v[3] = make_float2(fb.z, fb.w);
    }
  }

  if (!FINAL) {
    unsigned base = b + ((t & 1u) << 9) + ((t >> 1) << 10);
    outPsi[base]              = pack2(v[0], v[2]);
    outPsi[base + (1u << 18)] = pack2(v[1], v[3]);
  } else {
    float xv0 = xval(v[0]), xv1 = xval(v[1]), xv2 = xval(v[2]), xv3 = xval(v[3]);
    float s = xv0 + xv1 + xv2 + xv3;
    float2* o2 = (float2*)out;
    unsigned rt = __brev(t) >> 23, rb = __brev(b) >> 23;
    unsigned base = rt + (rb << 9);
    o2[base] = make_float2(xv0, xv1);
    o2[base + (1u << 18)] = make_float2(xv2, xv3);
#pragma unroll
    for (int o = 32; o > 0; o >>= 1) s += __shfl_down(s, o);
    if ((t & 63u) == 0) red[t >> 6] = s;
    __syncthreads();
    if (t == 0) {
      float tot = 0.f;
#pragma unroll
      for (int i = 0; i < 8; i++) tot += red[i];
      atomicAdd(accum, tot);
    }
  }
}

// Merged INIT + S1(0) (in-LDS, every block replicates the 2^11-amp sim)
// + handoff + S2(0). Writes outPsi (fp16) in the standard inter-pass layout.
__global__ __launch_bounds__(NT, 4) void init2_k(const float* __restrict__ u3p,
                                                 const float* __restrict__ cu3p,
                                                 h4* __restrict__ outPsi,
                                                 float* __restrict__ accum) {
  __shared__ float4 A4[1024], B4[1024];
  __shared__ float2 M[168];
  unsigned t = threadIdx.x, b = blockIdx.x;

  float2 v[4];
  v[0] = v[1] = v[2] = v[3] = make_float2(0.f, 0.f);
  if (t == 0) v[0] = make_float2(1.f, 0.f);   // every block: |0..0> of the 11-qubit sim
  if (b == 0 && t == 0) *accum = 0.f;

  float2* MU = M;
  float2* MC = M + 80;
  load_mats(u3p, cu3p, 0, t, MU, MC);
  __syncthreads();

  // ---- S1(0) body, entirely in LDS/regs ----
#pragma unroll
  for (int p = 0; p < 10; ++p) {
    if (p == 0) applyU3b0(v, MU);
    applyF(v, MU + 4 * (p + 1), MC + 4 * p);
    if (p < 9) {
      float4* buf = (p & 1) ? B4 : A4;
      buf[SW(t)]        = make_float4(v[0].x, v[0].y, v[2].x, v[2].y);
      buf[SW(t + 512u)] = make_float4(v[1].x, v[1].y, v[3].x, v[3].y);
      __syncthreads();
      float4 fa = buf[SW(2u * t)], fb = buf[SW(2u * t + 1u)];
      v[0] = make_float2(fa.x, fa.y); v[1] = make_float2(fa.z, fa.w);
      v[2] = make_float2(fb.x, fb.y); v[3] = make_float2(fb.z, fb.w);
    }
  }
  // S1 end: regs j=(q9,q10), t=(q0..q8). Stash psi1 into B4 (free: last
  // rotation used A4): psi1_idx = t + 512*j  (bit9=q9, bit10=q10).
  float2* lds1 = (float2*)B4;
  lds1[t]         = v[0];
  lds1[t + 512u]  = v[1];
  lds1[t + 1024u] = v[2];
  lds1[t + 1536u] = v[3];
  __syncthreads();

  // ---- handoff: S2 block b=(q1..q9); nonzero inputs need q11..q19=0 ->
  // t in {0,256} (q0=t>>8), regs j in {0,1} (q10=j):
  // psi1_idx = (t>>8) + (b<<1) + (j<<10).
  v[0] = v[1] = v[2] = v[3] = make_float2(0.f, 0.f);
  if ((t & 255u) == 0) {
    unsigned idx = (t >> 8) + (b << 1);
    v[0] = lds1[idx];
    v[1] = lds1[idx + 1024u];
  }
  // no barrier needed before first rotation write (targets A4, not B4);
  // B4 is first overwritten at rotation p=1, after p=0's barrier.

  // ---- S2(0) body ----
#pragma unroll
  for (int p = 0; p < 10; ++p) {
    if (p < 9) applyF(v, MU + 4 * (11 + p), MC + 4 * (10 + p));
    else       applyC(v, MC + 4 * 19);
    if (p < 9) {
      float4* buf = (p & 1) ? B4 : A4;
      buf[SW(t)]        = make_float4(v[0].x, v[0].y, v[2].x, v[2].y);
      buf[SW(t + 512u)] = make_float4(v[1].x, v[1].y, v[3].x, v[3].y);
      __syncthreads();
      float4 fa = buf[SW(2u * t)], fb = buf[SW(2u * t + 1u)];
      v[0] = make_float2(fa.x, fa.y); v[1] = make_float2(fa.z, fa.w);
      v[2] = make_float2(fb.x, fb.y); v[3] = make_float2(fb.z, fb.w);
    }
  }

  unsigned base = b + ((t & 1u) << 9) + ((t >> 1) << 10);
  outPsi[base]              = pack2(v[0], v[2]);
  outPsi[base + (1u << 18)] = pack2(v[1], v[3]);
}

__global__ void fin_k(float* __restrict__ out, const float* __restrict__ accum) {
  unsigned i = blockIdx.x * blockDim.x + threadIdx.x;
  float mean = *accum * (1.f / 1048576.f);
  float4* o4 = (float4*)out;
  float4 x = o4[i];
  x.x -= mean; x.y -= mean; x.z -= mean; x.w -= mean;
  o4[i] = x;
}

extern "C" void kernel_launch(void* const* d_in, const int* in_sizes, int n_in,
                              void* d_out, int out_size, void* d_ws, size_t ws_size,
                              hipStream_t stream) {
  const float* u3p = (const float*)d_in[0];
  const float* cu3p = (const float*)d_in[1];
  float* out = (float*)d_out;

  char* ws = (char*)d_ws;
  h4* psiA = (h4*)ws;                                      // 4 MB (fp16)
  h4* psiB = (h4*)(ws + (size_t)8 * 1024 * 1024);          // 4 MB (fp16)
  float* accum = (float*)(ws + (size_t)16 * 1024 * 1024);

  init2_k<<<NB, NT, 0, stream>>>(u3p, cu3p, psiA, accum);                       // L0
  pass_k<0, 0><<<NB, NT, 0, stream>>>(u3p, cu3p, 1, psiA, psiB, accum, out);    // S1(1)
  pass_k<1, 0><<<NB, NT, 0, stream>>>(u3p, cu3p, 1, psiB, psiA, accum, out);    // S2(1)
  pass_k<0, 0><<<NB, NT, 0, stream>>>(u3p, cu3p, 2, psiA, psiB, accum, out);    // S1(2)
  pass_k<1, 1><<<NB, NT, 0, stream>>>(u3p, cu3p, 2, psiB, nullptr, accum, out); // S2(2)+readout
  fin_k<<<1024, 256, 0, stream>>>(out, accum);
}

// Round 13
// 121.047 us; speedup vs baseline: 1.0668x; 1.0668x over previous
//
#include <hip/hip_runtime.h>
#include <cstdint>
#include <cstddef>

// 20-qubit statevector sim, 3 layers of [U3 x20 + CU3 ring (0,1)..(19,0)].
// R13 = R11 (127.5us, best) + precomputed gate-matrix tables.
// R12 (fp16 psi) regressed: I/O bytes don't matter; T_pass ~10.3us is
// fixed-cost dominated. Last visible serial component: the per-pass matrix
// stage (40 threads x 4-8 dependent sincosf while 512 threads wait at the
// barrier). These 120 matrices are identical across blocks/iterations:
// init2 block 0 precomputes layers 1,2 into a 2.5KB global table
// (matbuf at ws+16MB+256B; workspace is ~268MB per poison WRITE_SIZE);
// passes load 160 float2 with one 8B load/thread instead of sincos.
//
// Structure (6 dispatches): init2 (INIT+S1(0) in-LDS + handoff + S2(0)
// + matrix precompute), S1(1), S2(1), S1(2), S2(2)+readout, fin_k.
// Pass internals (R3, verified): NT=512, v[4], 512 blocks, 11-bit tiles;
// window bits (0,1); rotate-by-1 x9 via LDS double-buffer (XOR-swizzle);
// U3+CU3 fused per phase (W0, W1 = u_c*U3 precomputed).
// S1(k): U3 q0..q10 + CU3 (0,1)..(9,10); S2(k): U3 q11..q19 + CU3
// (10,11)..(19,0), tile=(q10,...,q19,q0), block=(q1..q9).
// Inter-pass store (verified): f4 = b + t0*2^9 + (t>>1)*2^10 + j0*2^18,
// content pairs over j1; reader loads contiguous 32B/thread.
// init2 handoff: after S1(0), psi nonzero only at q11..q19=0; S2(0) block
// b synthesizes its 4 inputs from the stashed 2^11-amp psi1 in LDS:
// psi1_idx = (t>>8) + (b<<1) + (j<<10), nonzero only for (t&255)==0.
// Final readout: R = j0 + 2*rev9(t) + 1024*rev9(b) + 2^19*j1; block sum
// -> atomicAdd(accum); fin_k subtracts mean.
// matbuf layout (float2): layer k in {1,2}: base=(k-1)*160; MU[4q] at
// base+4q, MC[4c] at base+80+4c (MC[c]=u_c*U3(c+1) fused; MC[19]=raw u19).

#define NB 512
#define NT 512
#define SW(i) ((i) ^ (((i) >> 3) & 1u))

__device__ __forceinline__ float2 cmadd2(float2 m0, float2 a0, float2 m1, float2 a1) {
  float2 r;
  r.x = m0.x * a0.x - m0.y * a0.y + m1.x * a1.x - m1.y * a1.y;
  r.y = m0.x * a0.y + m0.y * a0.x + m1.x * a1.y + m1.y * a1.x;
  return r;
}
__device__ __forceinline__ float2 cmul(float2 a, float2 b) {
  return make_float2(a.x * b.x - a.y * b.y, a.x * b.y + a.y * b.x);
}
__device__ __forceinline__ float2 cadd(float2 a, float2 b) {
  return make_float2(a.x + b.x, a.y + b.y);
}

// U3 on window bit0: pairs (0,1),(2,3)
__device__ __forceinline__ void applyU3b0(float2* v, const float2* m) {
  float2 m00 = m[0], m01 = m[1], m10 = m[2], m11 = m[3];
  float2 a0 = v[0], a1 = v[1];
  v[0] = cmadd2(m00, a0, m01, a1); v[1] = cmadd2(m10, a0, m11, a1);
  a0 = v[2]; a1 = v[3];
  v[2] = cmadd2(m00, a0, m01, a1); v[3] = cmadd2(m10, a0, m11, a1);
}
// fused [U3 on bit1, then CU3(ctrl=bit0,tgt=bit1)]: W0 acts on (v0,v2), W1 on (v1,v3)
__device__ __forceinline__ void applyF(float2* v, const float2* W0, const float2* W1) {
  float2 a0 = v[0], a1 = v[2];
  v[0] = cmadd2(W0[0], a0, W0[1], a1); v[2] = cmadd2(W0[2], a0, W0[3], a1);
  a0 = v[1]; a1 = v[3];
  v[1] = cmadd2(W1[0], a0, W1[1], a1); v[3] = cmadd2(W1[2], a0, W1[3], a1);
}
// raw CU3 ctrl bit0, tgt bit1: only (v1,v3)
__device__ __forceinline__ void applyC(float2* v, const float2* u) {
  float2 a0 = v[1], a1 = v[3];
  v[1] = cmadd2(u[0], a0, u[1], a1); v[3] = cmadd2(u[2], a0, u[3], a1);
}

__device__ __forceinline__ float xval(float2 a) {
  float p = a.x * a.x + a.y * a.y;
  return powf(0.8f * tanhf(52428.8f * p), 0.3f);
}

__device__ __forceinline__ void mat_from(const float* s, float2* m) {
  float st, ct, sl, cl, sp, cp, spl, cpl;
  sincosf(0.5f * s[0], &st, &ct);
  sincosf(s[2], &sl, &cl);
  sincosf(s[1], &sp, &cp);
  sincosf(s[1] + s[2], &spl, &cpl);
  m[0] = make_float2(ct, 0.f);
  m[1] = make_float2(-cl * st, -sl * st);
  m[2] = make_float2(cp * st, sp * st);
  m[3] = make_float2(cpl * ct, spl * ct);
}

// fused W1 for link c of layer k: u_c * U3(c+1); c==19 -> raw u_19.
__device__ __forceinline__ void fused_from(const float* u3p, const float* cu3p,
                                           int k, unsigned c, float2* dst) {
  float2 u[4];
  mat_from(cu3p + (k * 20 + c) * 3, u);
  if (c == 19) {
    dst[0] = u[0]; dst[1] = u[1]; dst[2] = u[2]; dst[3] = u[3];
  } else {
    float2 ut[4];
    mat_from(u3p + (k * 20 + c + 1) * 3, ut);
    dst[0] = cadd(cmul(u[0], ut[0]), cmul(u[1], ut[2]));
    dst[1] = cadd(cmul(u[0], ut[1]), cmul(u[1], ut[3]));
    dst[2] = cadd(cmul(u[2], ut[0]), cmul(u[3], ut[2]));
    dst[3] = cadd(cmul(u[2], ut[1]), cmul(u[3], ut[3]));
  }
}

// TYPE 0 = S1, 1 = S2; FINAL does readout. Matrices come from matbuf.
template <int TYPE, int FINAL>
__global__ __launch_bounds__(NT, 4) void pass_k(const float2* __restrict__ matbuf,
                                                int k,
                                                const float2* __restrict__ in,
                                                float2* __restrict__ outPsi,
                                                float* __restrict__ accum,
                                                float* __restrict__ out) {
  __shared__ float4 A4[1024], B4[1024];  // rotation double-buffer (16 KB each)
  __shared__ float2 M[168];
  __shared__ float red[8];
  unsigned t = threadIdx.x, b = blockIdx.x;

  float2 v[4];
  {
    const float4* in4 = (const float4*)in + ((size_t)b << 10) + 2u * t;
    float4 f0 = in4[0], f1 = in4[1];
    v[0] = make_float2(f0.x, f0.y); v[1] = make_float2(f0.z, f0.w);
    v[2] = make_float2(f1.x, f1.y); v[3] = make_float2(f1.z, f1.w);
  }
  // matrix table: one 8B load per thread (t<160) instead of sincos chains
  if (t < 160) M[t] = matbuf[(size_t)(k - 1) * 160 + t];
  __syncthreads();

  const float2* MU = M;
  const float2* MC = M + 80;
#pragma unroll
  for (int p = 0; p < 10; ++p) {
    if (TYPE == 0) {
      if (p == 0) applyU3b0(v, MU);
      applyF(v, MU + 4 * (p + 1), MC + 4 * p);
    } else {
      if (p < 9) applyF(v, MU + 4 * (11 + p), MC + 4 * (10 + p));
      else       applyC(v, MC + 4 * 19);
    }
    if (p < 9) {
      float4* buf = (p & 1) ? B4 : A4;
      buf[SW(t)]        = make_float4(v[0].x, v[0].y, v[2].x, v[2].y);
      buf[SW(t + 512u)] = make_float4(v[1].x, v[1].y, v[3].x, v[3].y);
      __syncthreads();
      float4 fa = buf[SW(2u * t)], fb = buf[SW(2u * t + 1u)];
      v[0] = make_float2(fa.x, fa.y); v[1] = make_float2(fa.z, fa.w);
      v[2] = make_float2(fb.x, fb.y); v[3] = make_float2(fb.z, fb.w);
    }
  }

  if (!FINAL) {
    float4* o4 = (float4*)outPsi;
    unsigned base = b + ((t & 1u) << 9) + ((t >> 1) << 10);
    o4[base]              = make_float4(v[0].x, v[0].y, v[2].x, v[2].y);
    o4[base + (1u << 18)] = make_float4(v[1].x, v[1].y, v[3].x, v[3].y);
  } else {
    float xv0 = xval(v[0]), xv1 = xval(v[1]), xv2 = xval(v[2]), xv3 = xval(v[3]);
    float s = xv0 + xv1 + xv2 + xv3;
    float2* o2 = (float2*)out;
    unsigned rt = __brev(t) >> 23, rb = __brev(b) >> 23;
    unsigned base = rt + (rb << 9);
    o2[base] = make_float2(xv0, xv1);
    o2[base + (1u << 18)] = make_float2(xv2, xv3);
#pragma unroll
    for (int o = 32; o > 0; o >>= 1) s += __shfl_down(s, o);
    if ((t & 63u) == 0) red[t >> 6] = s;
    __syncthreads();
    if (t == 0) {
      float tot = 0.f;
#pragma unroll
      for (int i = 0; i < 8; i++) tot += red[i];
      atomicAdd(accum, tot);
    }
  }
}

// Merged INIT + S1(0) (in-LDS) + handoff + S2(0), plus block 0 writes the
// layer-1/2 matrix tables to matbuf (consumed from the next dispatch on).
__global__ __launch_bounds__(NT, 4) void init2_k(const float* __restrict__ u3p,
                                                 const float* __restrict__ cu3p,
                                                 float2* __restrict__ outPsi,
                                                 float* __restrict__ accum,
                                                 float2* __restrict__ matbuf) {
  __shared__ float4 A4[1024], B4[1024];
  __shared__ float2 M[168];
  unsigned t = threadIdx.x, b = blockIdx.x;

  float2 v[4];
  v[0] = v[1] = v[2] = v[3] = make_float2(0.f, 0.f);
  if (t == 0) v[0] = make_float2(1.f, 0.f);   // every block: |0..0> of the 11-qubit sim
  if (b == 0 && t == 0) *accum = 0.f;

  // layer-0 matrices into LDS (same as before)
  float2* MU = M;
  float2* MC = M + 80;
  if (t < 20) {
    mat_from(u3p + t * 3, MU + 4 * t);
  } else if (t >= 64 && t < 84) {
    fused_from(u3p, cu3p, 0, t - 64, MC + 4 * (t - 64));
  }
  // block 0: precompute layer 1,2 tables to global (disjoint thread sets;
  // overlaps the layer-0 stage / main sim of other waves)
  if (b == 0) {
    if (t >= 128 && t < 148) {
      float2 m[4];
      mat_from(u3p + (20 + (t - 128)) * 3, m);
      float2* d = matbuf + 4 * (t - 128);
      d[0] = m[0]; d[1] = m[1]; d[2] = m[2]; d[3] = m[3];
    } else if (t >= 192 && t < 212) {
      float2 m[4];
      fused_from(u3p, cu3p, 1, t - 192, m);
      float2* d = matbuf + 80 + 4 * (t - 192);
      d[0] = m[0]; d[1] = m[1]; d[2] = m[2]; d[3] = m[3];
    } else if (t >= 256 && t < 276) {
      float2 m[4];
      mat_from(u3p + (40 + (t - 256)) * 3, m);
      float2* d = matbuf + 160 + 4 * (t - 256);
      d[0] = m[0]; d[1] = m[1]; d[2] = m[2]; d[3] = m[3];
    } else if (t >= 320 && t < 340) {
      float2 m[4];
      fused_from(u3p, cu3p, 2, t - 320, m);
      float2* d = matbuf + 240 + 4 * (t - 320);
      d[0] = m[0]; d[1] = m[1]; d[2] = m[2]; d[3] = m[3];
    }
  }
  __syncthreads();

  // ---- S1(0) body, entirely in LDS/regs ----
#pragma unroll
  for (int p = 0; p < 10; ++p) {
    if (p == 0) applyU3b0(v, MU);
    applyF(v, MU + 4 * (p + 1), MC + 4 * p);
    if (p < 9) {
      float4* buf = (p & 1) ? B4 : A4;
      buf[SW(t)]        = make_float4(v[0].x, v[0].y, v[2].x, v[2].y);
      buf[SW(t + 512u)] = make_float4(v[1].x, v[1].y, v[3].x, v[3].y);
      __syncthreads();
      float4 fa = buf[SW(2u * t)], fb = buf[SW(2u * t + 1u)];
      v[0] = make_float2(fa.x, fa.y); v[1] = make_float2(fa.z, fa.w);
      v[2] = make_float2(fb.x, fb.y); v[3] = make_float2(fb.z, fb.w);
    }
  }
  // S1 end: regs j=(q9,q10), t=(q0..q8). Stash psi1 into B4 (free: last
  // rotation used A4): psi1_idx = t + 512*j  (bit9=q9, bit10=q10).
  float2* lds1 = (float2*)B4;
  lds1[t]         = v[0];
  lds1[t + 512u]  = v[1];
  lds1[t + 1024u] = v[2];
  lds1[t + 1536u] = v[3];
  __syncthreads();

  // ---- handoff: S2 block b=(q1..q9); nonzero inputs need q11..q19=0 ->
  // t in {0,256} (q0=t>>8), regs j in {0,1} (q10=j):
  // psi1_idx = (t>>8) + (b<<1) + (j<<10).
  v[0] = v[1] = v[2] = v[3] = make_float2(0.f, 0.f);
  if ((t & 255u) == 0) {
    unsigned idx = (t >> 8) + (b << 1);
    v[0] = lds1[idx];
    v[1] = lds1[idx + 1024u];
  }
  // no barrier needed before first rotation write (targets A4, not B4);
  // B4 is first overwritten at rotation p=1, after p=0's barrier.

  // ---- S2(0) body ----
#pragma unroll
  for (int p = 0; p < 10; ++p) {
    if (p < 9) applyF(v, MU + 4 * (11 + p), MC + 4 * (10 + p));
    else       applyC(v, MC + 4 * 19);
    if (p < 9) {
      float4* buf = (p & 1) ? B4 : A4;
      buf[SW(t)]        = make_float4(v[0].x, v[0].y, v[2].x, v[2].y);
      buf[SW(t + 512u)] = make_float4(v[1].x, v[1].y, v[3].x, v[3].y);
      __syncthreads();
      float4 fa = buf[SW(2u * t)], fb = buf[SW(2u * t + 1u)];
      v[0] = make_float2(fa.x, fa.y); v[1] = make_float2(fa.z, fa.w);
      v[2] = make_float2(fb.x, fb.y); v[3] = make_float2(fb.z, fb.w);
    }
  }

  float4* o4 = (float4*)outPsi;
  unsigned base = b + ((t & 1u) << 9) + ((t >> 1) << 10);
  o4[base]              = make_float4(v[0].x, v[0].y, v[2].x, v[2].y);
  o4[base + (1u << 18)] = make_float4(v[1].x, v[1].y, v[3].x, v[3].y);
}

__global__ void fin_k(float* __restrict__ out, const float* __restrict__ accum) {
  unsigned i = blockIdx.x * blockDim.x + threadIdx.x;
  float mean = *accum * (1.f / 1048576.f);
  float4* o4 = (float4*)out;
  float4 x = o4[i];
  x.x -= mean; x.y -= mean; x.z -= mean; x.w -= mean;
  o4[i] = x;
}

extern "C" void kernel_launch(void* const* d_in, const int* in_sizes, int n_in,
                              void* d_out, int out_size, void* d_ws, size_t ws_size,
                              hipStream_t stream) {
  const float* u3p = (const float*)d_in[0];
  const float* cu3p = (const float*)d_in[1];
  float* out = (float*)d_out;

  char* ws = (char*)d_ws;
  float2* psiA = (float2*)ws;                              // 8 MB
  float2* psiB = (float2*)(ws + (size_t)8 * 1024 * 1024);  // 8 MB
  float* accum = (float*)(ws + (size_t)16 * 1024 * 1024);
  float2* matbuf = (float2*)(ws + (size_t)16 * 1024 * 1024 + 256);  // 2.5 KB

  init2_k<<<NB, NT, 0, stream>>>(u3p, cu3p, psiA, accum, matbuf);            // L0
  pass_k<0, 0><<<NB, NT, 0, stream>>>(matbuf, 1, psiA, psiB, accum, out);    // S1(1)
  pass_k<1, 0><<<NB, NT, 0, stream>>>(matbuf, 1, psiB, psiA, accum, out);    // S2(1)
  pass_k<0, 0><<<NB, NT, 0, stream>>>(matbuf, 2, psiA, psiB, accum, out);    // S1(2)
  pass_k<1, 1><<<NB, NT, 0, stream>>>(matbuf, 2, psiB, nullptr, accum, out); // S2(2)+readout
  fin_k<<<1024, 256, 0, stream>>>(out, accum);
}

// Round 14
// 120.778 us; speedup vs baseline: 1.0692x; 1.0022x over previous
//
#include <hip/hip_runtime.h>
#include <cstdint>
#include <cstddef>

// 20-qubit statevector sim, 3 layers of [U3 x20 + CU3 ring (0,1)..(19,0)].
// R14 = R13 (121.0us, best) + PARALLEL sincos staging in init2.
// R13 removed the serial-sincos barrier gate from the 4 passes via matbuf
// (-6.5us); init2 still had it (fused_from = ~8 dependent sincosf ~2500cyc
// gating the whole block). Fix: stage A computes ONE sincos per thread
// into LDS SC[] (160 angles for layer 0 in all blocks; block 0 also 320
// for layers 1-2), then stage B assembles matrices 1 thread/gate
// (~10 mult / ~16 cmul). Gate ~2500 -> ~450 cyc.
//
// Structure (6 dispatches): init2 (INIT+S1(0) in-LDS + handoff + S2(0)
// + matbuf precompute), S1(1), S2(1), S1(2), S2(2)+readout, fin_k.
// Pass internals (R3, verified): NT=512, v[4], 512 blocks, 11-bit tiles;
// window bits (0,1); rotate-by-1 x9 via LDS double-buffer (XOR-swizzle);
// U3+CU3 fused per phase (W0, W1 = u_c*U3 precomputed).
// Inter-pass store (verified): f4 = b + t0*2^9 + (t>>1)*2^10 + j0*2^18,
// content pairs over j1; reader loads contiguous 32B/thread.
// init2 handoff: after S1(0), psi nonzero only at q11..q19=0; S2(0) block
// b synthesizes inputs from stashed 2^11-amp psi1 in LDS:
// psi1_idx = (t>>8) + (b<<1) + (j<<10), nonzero only for (t&255)==0.
// Final readout: R = j0 + 2*rev9(t) + 1024*rev9(b) + 2^19*j1; block sum
// -> atomicAdd(accum); fin_k subtracts mean.
// matbuf (float2): layer k in {1,2}: base=(k-1)*160; MU[4q], MC at +80.
// SC (float2, (sin,cos)): gate g in [0,40): g<20 U3(g), g>=20 CU3(g-20);
// angle a in {0:th/2, 1:phi, 2:lam, 3:phi+lam}; layer-0 at SC[4g+a],
// block-0 layers 1,2 at SC[160*(k) + ...] offsets 160/320.

#define NB 512
#define NT 512
#define SW(i) ((i) ^ (((i) >> 3) & 1u))

__device__ __forceinline__ float2 cmadd2(float2 m0, float2 a0, float2 m1, float2 a1) {
  float2 r;
  r.x = m0.x * a0.x - m0.y * a0.y + m1.x * a1.x - m1.y * a1.y;
  r.y = m0.x * a0.y + m0.y * a0.x + m1.x * a1.y + m1.y * a1.x;
  return r;
}
__device__ __forceinline__ float2 cmul(float2 a, float2 b) {
  return make_float2(a.x * b.x - a.y * b.y, a.x * b.y + a.y * b.x);
}
__device__ __forceinline__ float2 cadd(float2 a, float2 b) {
  return make_float2(a.x + b.x, a.y + b.y);
}

// U3 on window bit0: pairs (0,1),(2,3)
__device__ __forceinline__ void applyU3b0(float2* v, const float2* m) {
  float2 m00 = m[0], m01 = m[1], m10 = m[2], m11 = m[3];
  float2 a0 = v[0], a1 = v[1];
  v[0] = cmadd2(m00, a0, m01, a1); v[1] = cmadd2(m10, a0, m11, a1);
  a0 = v[2]; a1 = v[3];
  v[2] = cmadd2(m00, a0, m01, a1); v[3] = cmadd2(m10, a0, m11, a1);
}
// fused [U3 on bit1, then CU3(ctrl=bit0,tgt=bit1)]: W0 acts on (v0,v2), W1 on (v1,v3)
__device__ __forceinline__ void applyF(float2* v, const float2* W0, const float2* W1) {
  float2 a0 = v[0], a1 = v[2];
  v[0] = cmadd2(W0[0], a0, W0[1], a1); v[2] = cmadd2(W0[2], a0, W0[3], a1);
  a0 = v[1]; a1 = v[3];
  v[1] = cmadd2(W1[0], a0, W1[1], a1); v[3] = cmadd2(W1[2], a0, W1[3], a1);
}
// raw CU3 ctrl bit0, tgt bit1: only (v1,v3)
__device__ __forceinline__ void applyC(float2* v, const float2* u) {
  float2 a0 = v[1], a1 = v[3];
  v[1] = cmadd2(u[0], a0, u[1], a1); v[3] = cmadd2(u[2], a0, u[3], a1);
}

__device__ __forceinline__ float xval(float2 a) {
  float p = a.x * a.x + a.y * a.y;
  return powf(0.8f * tanhf(52428.8f * p), 0.3f);
}

// assemble a U3/CU3 matrix from 4 staged (sin,cos) pairs
__device__ __forceinline__ void asm_u3(const float2* sc, float2* m) {
  float st = sc[0].x, ct = sc[0].y;
  float sp = sc[1].x, cp = sc[1].y;
  float sl = sc[2].x, cl = sc[2].y;
  float spl = sc[3].x, cpl = sc[3].y;
  m[0] = make_float2(ct, 0.f);
  m[1] = make_float2(-cl * st, -sl * st);
  m[2] = make_float2(cp * st, sp * st);
  m[3] = make_float2(cpl * ct, spl * ct);
}
// fused W1 for link c: u_c * U3(c+1) (scC = CU3 pairs, scU = U3(c+1) pairs)
__device__ __forceinline__ void asm_fused(const float2* scC, const float2* scU,
                                          float2* d, bool raw) {
  float2 u[4];
  asm_u3(scC, u);
  if (raw) { d[0] = u[0]; d[1] = u[1]; d[2] = u[2]; d[3] = u[3]; return; }
  float2 w[4];
  asm_u3(scU, w);
  d[0] = cadd(cmul(u[0], w[0]), cmul(u[1], w[2]));
  d[1] = cadd(cmul(u[0], w[1]), cmul(u[1], w[3]));
  d[2] = cadd(cmul(u[2], w[0]), cmul(u[3], w[2]));
  d[3] = cadd(cmul(u[2], w[1]), cmul(u[3], w[3]));
}
// stage A helper: one sincos for (gate g, angle a) of layer k
__device__ __forceinline__ float2 stage_sc(const float* u3p, const float* cu3p,
                                           int k, unsigned g, unsigned a) {
  const float* s = (g < 20) ? (u3p + (k * 20 + g) * 3) : (cu3p + (k * 20 + (g - 20)) * 3);
  float ang = (a == 0) ? 0.5f * s[0] : (a == 1) ? s[1] : (a == 2) ? s[2] : s[1] + s[2];
  float sn, cs;
  sincosf(ang, &sn, &cs);
  return make_float2(sn, cs);
}

// TYPE 0 = S1, 1 = S2; FINAL does readout. Matrices come from matbuf.
template <int TYPE, int FINAL>
__global__ __launch_bounds__(NT, 4) void pass_k(const float2* __restrict__ matbuf,
                                                int k,
                                                const float2* __restrict__ in,
                                                float2* __restrict__ outPsi,
                                                float* __restrict__ accum,
                                                float* __restrict__ out) {
  __shared__ float4 A4[1024], B4[1024];  // rotation double-buffer (16 KB each)
  __shared__ float2 M[168];
  __shared__ float red[8];
  unsigned t = threadIdx.x, b = blockIdx.x;

  float2 v[4];
  {
    const float4* in4 = (const float4*)in + ((size_t)b << 10) + 2u * t;
    float4 f0 = in4[0], f1 = in4[1];
    v[0] = make_float2(f0.x, f0.y); v[1] = make_float2(f0.z, f0.w);
    v[2] = make_float2(f1.x, f1.y); v[3] = make_float2(f1.z, f1.w);
  }
  // matrix table: one 8B load per thread (t<160) instead of sincos chains
  if (t < 160) M[t] = matbuf[(size_t)(k - 1) * 160 + t];
  __syncthreads();

  const float2* MU = M;
  const float2* MC = M + 80;
#pragma unroll
  for (int p = 0; p < 10; ++p) {
    if (TYPE == 0) {
      if (p == 0) applyU3b0(v, MU);
      applyF(v, MU + 4 * (p + 1), MC + 4 * p);
    } else {
      if (p < 9) applyF(v, MU + 4 * (11 + p), MC + 4 * (10 + p));
      else       applyC(v, MC + 4 * 19);
    }
    if (p < 9) {
      float4* buf = (p & 1) ? B4 : A4;
      buf[SW(t)]        = make_float4(v[0].x, v[0].y, v[2].x, v[2].y);
      buf[SW(t + 512u)] = make_float4(v[1].x, v[1].y, v[3].x, v[3].y);
      __syncthreads();
      float4 fa = buf[SW(2u * t)], fb = buf[SW(2u * t + 1u)];
      v[0] = make_float2(fa.x, fa.y); v[1] = make_float2(fa.z, fa.w);
      v[2] = make_float2(fb.x, fb.y); v[3] = make_float2(fb.z, fb.w);
    }
  }

  if (!FINAL) {
    float4* o4 = (float4*)outPsi;
    unsigned base = b + ((t & 1u) << 9) + ((t >> 1) << 10);
    o4[base]              = make_float4(v[0].x, v[0].y, v[2].x, v[2].y);
    o4[base + (1u << 18)] = make_float4(v[1].x, v[1].y, v[3].x, v[3].y);
  } else {
    float xv0 = xval(v[0]), xv1 = xval(v[1]), xv2 = xval(v[2]), xv3 = xval(v[3]);
    float s = xv0 + xv1 + xv2 + xv3;
    float2* o2 = (float2*)out;
    unsigned rt = __brev(t) >> 23, rb = __brev(b) >> 23;
    unsigned base = rt + (rb << 9);
    o2[base] = make_float2(xv0, xv1);
    o2[base + (1u << 18)] = make_float2(xv2, xv3);
#pragma unroll
    for (int o = 32; o > 0; o >>= 1) s += __shfl_down(s, o);
    if ((t & 63u) == 0) red[t >> 6] = s;
    __syncthreads();
    if (t == 0) {
      float tot = 0.f;
#pragma unroll
      for (int i = 0; i < 8; i++) tot += red[i];
      atomicAdd(accum, tot);
    }
  }
}

// Merged INIT + S1(0) (in-LDS) + handoff + S2(0); parallel-sincos matrix
// staging; block 0 also writes the layer-1/2 tables to matbuf.
__global__ __launch_bounds__(NT, 4) void init2_k(const float* __restrict__ u3p,
                                                 const float* __restrict__ cu3p,
                                                 float2* __restrict__ outPsi,
                                                 float* __restrict__ accum,
                                                 float2* __restrict__ matbuf) {
  __shared__ float4 A4[1024], B4[1024];
  __shared__ float2 M[168];
  __shared__ float2 SC[480];  // (sin,cos) staging: L0 [0,160); L1 [160,320); L2 [320,480)
  unsigned t = threadIdx.x, b = blockIdx.x;

  float2 v[4];
  v[0] = v[1] = v[2] = v[3] = make_float2(0.f, 0.f);
  if (t == 0) v[0] = make_float2(1.f, 0.f);   // every block: |0..0> of the 11-qubit sim
  if (b == 0 && t == 0) *accum = 0.f;

  // ---- stage A: one sincos per thread ----
  if (t < 160) SC[t] = stage_sc(u3p, cu3p, 0, t >> 2, t & 3u);
  if (b == 0 && t >= 160 && t < 480) {
    int k = (t < 320) ? 1 : 2;
    unsigned r = t - (k == 1 ? 160u : 320u);
    SC[t] = stage_sc(u3p, cu3p, k, r >> 2, r & 3u);
  }
  __syncthreads();

  // ---- stage B: assemble matrices, 1 thread/gate ----
  float2* MU = M;
  float2* MC = M + 80;
  if (t < 20) {
    asm_u3(SC + 4 * t, MU + 4 * t);
  } else if (t < 40) {
    unsigned c = t - 20;
    asm_fused(SC + 4 * (20 + c), SC + 4 * (c + 1), MC + 4 * c, c == 19);
  }
  if (b == 0 && t >= 64 && t < 144) {
    int k = (t < 104) ? 1 : 2;
    unsigned g = t - (k == 1 ? 64u : 104u);
    const float2* sck = SC + 160 * k;
    float2 m[4];
    if (g < 20) asm_u3(sck + 4 * g, m);
    else        asm_fused(sck + 4 * g, sck + 4 * (g - 19), m, g == 39);
    float2* d = matbuf + (k - 1) * 160 + (g < 20 ? 4 * g : 80 + 4 * (g - 20));
    d[0] = m[0]; d[1] = m[1]; d[2] = m[2]; d[3] = m[3];
  }
  __syncthreads();

  // ---- S1(0) body, entirely in LDS/regs ----
#pragma unroll
  for (int p = 0; p < 10; ++p) {
    if (p == 0) applyU3b0(v, MU);
    applyF(v, MU + 4 * (p + 1), MC + 4 * p);
    if (p < 9) {
      float4* buf = (p & 1) ? B4 : A4;
      buf[SW(t)]        = make_float4(v[0].x, v[0].y, v[2].x, v[2].y);
      buf[SW(t + 512u)] = make_float4(v[1].x, v[1].y, v[3].x, v[3].y);
      __syncthreads();
      float4 fa = buf[SW(2u * t)], fb = buf[SW(2u * t + 1u)];
      v[0] = make_float2(fa.x, fa.y); v[1] = make_float2(fa.z, fa.w);
      v[2] = make_float2(fb.x, fb.y); v[3] = make_float2(fb.z, fb.w);
    }
  }
  // S1 end: regs j=(q9,q10), t=(q0..q8). Stash psi1 into B4 (free: last
  // rotation used A4): psi1_idx = t + 512*j  (bit9=q9, bit10=q10).
  float2* lds1 = (float2*)B4;
  lds1[t]         = v[0];
  lds1[t + 512u]  = v[1];
  lds1[t + 1024u] = v[2];
  lds1[t + 1536u] = v[3];
  __syncthreads();

  // ---- handoff: S2 block b=(q1..q9); nonzero inputs need q11..q19=0 ->
  // t in {0,256} (q0=t>>8), regs j in {0,1} (q10=j):
  // psi1_idx = (t>>8) + (b<<1) + (j<<10).
  v[0] = v[1] = v[2] = v[3] = make_float2(0.f, 0.f);
  if ((t & 255u) == 0) {
    unsigned idx = (t >> 8) + (b << 1);
    v[0] = lds1[idx];
    v[1] = lds1[idx + 1024u];
  }
  // no barrier needed before first rotation write (targets A4, not B4);
  // B4 is first overwritten at rotation p=1, after p=0's barrier.

  // ---- S2(0) body ----
#pragma unroll
  for (int p = 0; p < 10; ++p) {
    if (p < 9) applyF(v, MU + 4 * (11 + p), MC + 4 * (10 + p));
    else       applyC(v, MC + 4 * 19);
    if (p < 9) {
      float4* buf = (p & 1) ? B4 : A4;
      buf[SW(t)]        = make_float4(v[0].x, v[0].y, v[2].x, v[2].y);
      buf[SW(t + 512u)] = make_float4(v[1].x, v[1].y, v[3].x, v[3].y);
      __syncthreads();
      float4 fa = buf[SW(2u * t)], fb = buf[SW(2u * t + 1u)];
      v[0] = make_float2(fa.x, fa.y); v[1] = make_float2(fa.z, fa.w);
      v[2] = make_float2(fb.x, fb.y); v[3] = make_float2(fb.z, fb.w);
    }
  }

  float4* o4 = (float4*)outPsi;
  unsigned base = b + ((t & 1u) << 9) + ((t >> 1) << 10);
  o4[base]              = make_float4(v[0].x, v[0].y, v[2].x, v[2].y);
  o4[base + (1u << 18)] = make_float4(v[1].x, v[1].y, v[3].x, v[3].y);
}

__global__ void fin_k(float* __restrict__ out, const float* __restrict__ accum) {
  unsigned i = blockIdx.x * blockDim.x + threadIdx.x;
  float mean = *accum * (1.f / 1048576.f);
  float4* o4 = (float4*)out;
  float4 x = o4[i];
  x.x -= mean; x.y -= mean; x.z -= mean; x.w -= mean;
  o4[i] = x;
}

extern "C" void kernel_launch(void* const* d_in, const int* in_sizes, int n_in,
                              void* d_out, int out_size, void* d_ws, size_t ws_size,
                              hipStream_t stream) {
  const float* u3p = (const float*)d_in[0];
  const float* cu3p = (const float*)d_in[1];
  float* out = (float*)d_out;

  char* ws = (char*)d_ws;
  float2* psiA = (float2*)ws;                              // 8 MB
  float2* psiB = (float2*)(ws + (size_t)8 * 1024 * 1024);  // 8 MB
  float* accum = (float*)(ws + (size_t)16 * 1024 * 1024);
  float2* matbuf = (float2*)(ws + (size_t)16 * 1024 * 1024 + 256);  // 2.5 KB

  init2_k<<<NB, NT, 0, stream>>>(u3p, cu3p, psiA, accum, matbuf);            // L0
  pass_k<0, 0><<<NB, NT, 0, stream>>>(matbuf, 1, psiA, psiB, accum, out);    // S1(1)
  pass_k<1, 0><<<NB, NT, 0, stream>>>(matbuf, 1, psiB, psiA, accum, out);    // S2(1)
  pass_k<0, 0><<<NB, NT, 0, stream>>>(matbuf, 2, psiA, psiB, accum, out);    // S1(2)
  pass_k<1, 1><<<NB, NT, 0, stream>>>(matbuf, 2, psiB, nullptr, accum, out); // S2(2)+readout
  fin_k<<<1024, 256, 0, stream>>>(out, accum);
}